// Round 2
// 668.403 us; speedup vs baseline: 1.0039x; 1.0039x over previous
//
#include <hip/hip_runtime.h>

// Problem: EBCNN — B=8192, S=30, D=512, H=1024, L_K=3
//   feature[b] = [ max_i conv3 w_long | max last-5 conv3 w_mid | emb[b,29,:] ]
//   out[b] = sum_h W2[h] * tanh( feature[b] . W1[h] )
//
// ws layout: feature bf16 [8192*1536] then W1 bf16 [1024*1536]  (~28.3 MB)
//
// R5 (re-run; previous attempt hit an infra failure, no signal): GEMM only.
//  (a) LDS double-buffer: stage(kt+1) issued BEFORE compute(kt), so the
//      compiler's vmcnt(0)-drain before the barrier pays only the residual
//      latency (load latency overlapped with 32 MFMAs + 16 ds_read_b128).
//      Single-buffered version exposed the full global->LDS round trip on
//      every one of the 24 K-steps with only 2 blocks/CU to hide it.
//  (b) Bijective XCD swizzle (T1): hw blockIdx round-robins the 8 XCDs;
//      logical = (bid&7)*64 + (bid>>3) puts each m-panel's 8 n-blocks on ONE
//      XCD (all co-resident: 64 blocks/XCD = 32 CU x 2). A panel fetched once
//      per XCD instead of 8x (200MB -> ~28MB); B (3MB) becomes L2-resident.
// feat/w1conv untouched (feat ~HBM-bound at ~100us, floor 84us).

#define B_   8192
#define S_   30
#define D_   512
#define H_   1024
#define K_   1536   // 3*D

typedef float nf4 __attribute__((ext_vector_type(4)));

// ---------- helpers ----------
__device__ inline unsigned short f2bf(float f) {
    unsigned int u = __float_as_uint(f);
    u += 0x7FFFu + ((u >> 16) & 1u);   // RNE
    return (unsigned short)(u >> 16);
}

__device__ inline nf4 fmax4(nf4 a, nf4 b) {
    nf4 r;
    r.x = fmaxf(a.x, b.x); r.y = fmaxf(a.y, b.y);
    r.z = fmaxf(a.z, b.z); r.w = fmaxf(a.w, b.w);
    return r;
}

__device__ inline void store_bf4(unsigned short* p, nf4 v) {
    ushort4 o;
    o.x = f2bf(v.x); o.y = f2bf(v.y); o.z = f2bf(v.z); o.w = f2bf(v.w);
    *(ushort4*)p = o;
}

__device__ inline nf4 ntload4(const float* p) {
    return __builtin_nontemporal_load((const nf4*)p);
}

__device__ inline float fast_tanh(float x) {
    float cx = fminf(fmaxf(x, -15.f), 15.f);
    float e = __expf(2.f * cx);            // v_exp_f32 path
    return (e - 1.f) / (e + 1.f);
}

// ---------- kernel 1: feature extraction ----------
__global__ __launch_bounds__(256) void feat_kernel(
    const float* __restrict__ emb, const float* __restrict__ wl,
    const float* __restrict__ wm, unsigned short* __restrict__ feat)
{
    int gid = blockIdx.x * 256 + threadIdx.x;     // 0 .. B*128-1
    int b   = gid >> 7;
    int c4  = (gid & 127) << 2;                   // channel base

    const float* base = emb + (size_t)b * (S_ * D_) + c4;
    const float l0 = wl[0], l1 = wl[1], l2 = wl[2];
    const float m0 = wm[0], m1 = wm[1], m2 = wm[2];

    nf4 e0 = ntload4(base + 0 * D_);
    nf4 e1 = ntload4(base + 1 * D_);
    nf4 vl = {-3.4e38f, -3.4e38f, -3.4e38f, -3.4e38f};
    nf4 vm = vl;

    #pragma unroll 4
    for (int i = 0; i < 28; ++i) {
        nf4 e2 = ntload4(base + (i + 2) * D_);
        nf4 cv = e0 * l0 + e1 * l1 + e2 * l2;
        vl = fmax4(vl, cv);
        if (i >= 23) {                            // wave-uniform branch
            nf4 cm = e0 * m0 + e1 * m1 + e2 * m2;
            vm = fmax4(vm, cm);
        }
        e0 = e1; e1 = e2;
    }
    unsigned short* frow = feat + (size_t)b * K_;
    store_bf4(frow + c4,            vl);
    store_bf4(frow + D_ + c4,       vm);
    store_bf4(frow + 2 * D_ + c4,   e1);
}

// ---------- kernel 2: W1 fp32 -> bf16 ----------
__global__ __launch_bounds__(256) void w1conv_kernel(
    const float* __restrict__ W1, unsigned short* __restrict__ w1b)
{
    int gid = blockIdx.x * 256 + threadIdx.x;     // H_*K_/4 threads
    nf4 v = ((const nf4*)W1)[gid];
    ushort4 o;
    o.x = f2bf(v.x); o.y = f2bf(v.y); o.z = f2bf(v.z); o.w = f2bf(v.w);
    ((ushort4*)w1b)[gid] = o;
}

// ---------- kernel 3: GEMM (feature @ W1^T) + tanh + W2 reduce ----------
// M=8192, N=1024, K=1536, both operands K-contiguous. 128x128 tile, BK=64,
// 4 waves 2x2, each wave 64x64 via 4x4 MFMA 16x16x32 bf16.
// LDS: 2 x (128 rows x 64 k) per operand, stored as 16B chunks; physical
// chunk within a row is XOR-swizzled: phys_j = j ^ (row&7). global_load_lds
// dst stays tid-linear (wave-uniform + lane*16 requirement); the *source*
// chunk is permuted. Fragment read (row r, chunk j) -> addr r*128B +
// (j^(r&7))*16B: banks spread across all 32, 2-way = free per m136.

typedef __bf16 bf16x8 __attribute__((ext_vector_type(8)));
typedef float  f32x4  __attribute__((ext_vector_type(4)));

#define GL2LDS(gp, lp) __builtin_amdgcn_global_load_lds( \
    (const __attribute__((address_space(1))) void*)(gp), \
    (__attribute__((address_space(3))) void*)(lp), 16, 0, 0)

#define NT_ (K_ / 64)   // 24 K-steps

__global__ __launch_bounds__(256) void gemm_kernel(
    const unsigned short* __restrict__ A,    // feature bf16 [8192][1536]
    const unsigned short* __restrict__ Bm,   // W1 bf16 [1024][1536]
    const float* __restrict__ W2,            // [1024]
    float* __restrict__ out)                 // [8192]
{
    __shared__ unsigned short As[2][128 * 64];  // 2 x 16 KB
    __shared__ unsigned short Bs[2][128 * 64];  // 2 x 16 KB

    const int tid  = threadIdx.x;

    // Bijective XCD swizzle (512 blocks, 512%8==0): XCD x gets logical ids
    // [64x, 64x+64) = m-panels 8x..8x+7 with ALL 8 n-blocks each, co-resident.
    const int lg   = (blockIdx.x & 7) * 64 + (blockIdx.x >> 3);
    const int bm   = (lg >> 3) * 128;           // 64 m-blocks
    const int bn   = (lg & 7) * 128;            // 8 n-blocks

    const int lane = tid & 63;
    const int wm   = (tid >> 6) >> 1;           // 0..1 (m half)
    const int wn   = (tid >> 6) & 1;            // 0..1 (n half)
    const int lrow = lane & 15;
    const int quad = lane >> 4;

    f32x4 acc[4][4] = {};

    // staging: thread t handles chunks q = t + jj*256, jj=0..3, for A and B.
    // chunk q: row = q>>3, swizzled slot jsw = q&7 -> global j = jsw ^ (row&7).
    int s_row[4], s_jof[4];
    #pragma unroll
    for (int jj = 0; jj < 4; ++jj) {
        int q = tid + jj * 256;
        s_row[jj] = q >> 3;
        s_jof[jj] = (((q & 7) ^ (s_row[jj] & 7)) * 8);
    }

    auto stage = [&](int buf, int kt) {
        const int ko = kt * 64;
        #pragma unroll
        for (int jj = 0; jj < 4; ++jj) {
            int q = tid + jj * 256;
            GL2LDS(A  + (size_t)(bm + s_row[jj]) * K_ + ko + s_jof[jj], &As[buf][q * 8]);
            GL2LDS(Bm + (size_t)(bn + s_row[jj]) * K_ + ko + s_jof[jj], &Bs[buf][q * 8]);
        }
    };

    // prologue: fill buffer 0
    stage(0, 0);
    __syncthreads();   // vmcnt(0) drain + barrier

    for (int kt = 0; kt < NT_; ++kt) {
        const int cur = kt & 1;
        // issue next tile's loads BEFORE compute: their latency hides under
        // the 16 ds_read_b128 + 32 MFMAs below; the vmcnt(0) drain at the
        // end-of-iteration barrier only pays the residual.
        if (kt + 1 < NT_) stage(cur ^ 1, kt + 1);

        #pragma unroll
        for (int kk = 0; kk < 2; ++kk) {
            bf16x8 af[4], bf[4];
            const int j = kk * 4 + quad;
            #pragma unroll
            for (int mi = 0; mi < 4; ++mi) {
                int r = wm * 64 + mi * 16 + lrow;
                af[mi] = *(const bf16x8*)&As[cur][r * 64 + ((j ^ (r & 7)) * 8)];
            }
            #pragma unroll
            for (int ni = 0; ni < 4; ++ni) {
                int r = wn * 64 + ni * 16 + lrow;
                bf[ni] = *(const bf16x8*)&Bs[cur][r * 64 + ((j ^ (r & 7)) * 8)];
            }
            #pragma unroll
            for (int mi = 0; mi < 4; ++mi)
                #pragma unroll
                for (int ni = 0; ni < 4; ++ni)
                    acc[mi][ni] = __builtin_amdgcn_mfma_f32_16x16x32_bf16(
                        af[mi], bf[ni], acc[mi][ni], 0, 0, 0);
        }

        __syncthreads();   // drains stage(kt+1); protects As/Bs[cur] reuse
    }

    // epilogue: row = bm + wm*64 + mi*16 + quad*4 + r, col = bn + wn*64 + ni*16 + lrow
    float w2v[4];
    #pragma unroll
    for (int ni = 0; ni < 4; ++ni)
        w2v[ni] = W2[bn + wn * 64 + ni * 16 + lrow];

    #pragma unroll
    for (int mi = 0; mi < 4; ++mi) {
        #pragma unroll
        for (int r = 0; r < 4; ++r) {
            float s = 0.f;
            #pragma unroll
            for (int ni = 0; ni < 4; ++ni)
                s += fast_tanh(acc[mi][ni][r]) * w2v[ni];
            #pragma unroll
            for (int off = 1; off < 16; off <<= 1)
                s += __shfl_xor(s, off, 64);
            if (lrow == 0)
                atomicAdd(&out[bm + wm * 64 + mi * 16 + quad * 4 + r], s);
        }
    }
}

extern "C" void kernel_launch(void* const* d_in, const int* in_sizes, int n_in,
                              void* d_out, int out_size, void* d_ws, size_t ws_size,
                              hipStream_t stream) {
    const float* emb = (const float*)d_in[0];   // [8192,30,512]
    const float* wl  = (const float*)d_in[1];   // [3]
    const float* wm  = (const float*)d_in[2];   // [3]
    const float* W1  = (const float*)d_in[3];   // [1024,1536]
    const float* W2  = (const float*)d_in[4];   // [1,1024]
    float* out = (float*)d_out;                 // [8192]

    unsigned short* feat = (unsigned short*)d_ws;            // 8192*1536 bf16
    unsigned short* w1b  = feat + (size_t)B_ * K_;           // 1024*1536 bf16

    (void)hipMemsetAsync(out, 0, sizeof(float) * B_, stream);  // atomics target

    hipLaunchKernelGGL(feat_kernel, dim3(B_ * (D_ / 4) / 256), dim3(256), 0, stream,
                       emb, wl, wm, feat);
    hipLaunchKernelGGL(w1conv_kernel, dim3(H_ * K_ / 4 / 256), dim3(256), 0, stream,
                       W1, w1b);
    hipLaunchKernelGGL(gemm_kernel, dim3((B_ / 128) * (H_ / 128)), dim3(256), 0, stream,
                       feat, w1b, W2, out);
}

// Round 3
// 657.727 us; speedup vs baseline: 1.0202x; 1.0162x over previous
//
#include <hip/hip_runtime.h>

// Problem: EBCNN — B=8192, S=30, D=512, H=1024, L_K=3
//   feature[b] = [ max_i conv3 w_long | max last-5 conv3 w_mid | emb[b,29,:] ]
//   out[b] = sum_h W2[h] * tanh( feature[b] . W1[h] )
//
// ws layout: feature bf16 [8192*1536] then W1 bf16 [1024*1536]  (~28.3 MB)
//
// R6: discriminating probe + launch fusion.
//  (a) gemm: 512 threads / 8 waves (2m x 4n), same 128x128 tile + BK=64 dbuf
//      + XCD swizzle. Waves/CU 8->16 (2->4 per SIMD). If gemm was secretly
//      latency/occupancy-bound (~250us candidate from window arithmetic),
//      this cuts it hard; if gemm is ~12us as modeled, this is neutral.
//      (Top-5 rocprof rows are saturated by ~310us/iter ws-poison fills, so
//      gemm counters are invisible — this probe discriminates by dur_us.)
//  (b) prep_kernel = feat + w1conv + out-zeroing fused into ONE launch
//      (block-uniform branch on blockIdx): removes 2 dispatches; w1conv's
//      9 MB hides under feat's 503 MB stream. Replaces hipMemsetAsync(out).

#define B_   8192
#define S_   30
#define D_   512
#define H_   1024
#define K_   1536   // 3*D

typedef float nf4 __attribute__((ext_vector_type(4)));

// ---------- helpers ----------
__device__ inline unsigned short f2bf(float f) {
    unsigned int u = __float_as_uint(f);
    u += 0x7FFFu + ((u >> 16) & 1u);   // RNE
    return (unsigned short)(u >> 16);
}

__device__ inline nf4 fmax4(nf4 a, nf4 b) {
    nf4 r;
    r.x = fmaxf(a.x, b.x); r.y = fmaxf(a.y, b.y);
    r.z = fmaxf(a.z, b.z); r.w = fmaxf(a.w, b.w);
    return r;
}

__device__ inline void store_bf4(unsigned short* p, nf4 v) {
    ushort4 o;
    o.x = f2bf(v.x); o.y = f2bf(v.y); o.z = f2bf(v.z); o.w = f2bf(v.w);
    *(ushort4*)p = o;
}

__device__ inline nf4 ntload4(const float* p) {
    return __builtin_nontemporal_load((const nf4*)p);
}

__device__ inline float fast_tanh(float x) {
    float cx = fminf(fmaxf(x, -15.f), 15.f);
    float e = __expf(2.f * cx);            // v_exp_f32 path
    return (e - 1.f) / (e + 1.f);
}

// ---------- kernel 1: fused prep = feat | w1conv | zero(out) ----------
#define FEAT_BLKS  (B_ * (D_ / 4) / 256)   // 4096
#define W1C_BLKS   (H_ * K_ / 4 / 256)     // 1536
#define ZERO_BLKS  (B_ / (256 * 4))        // 8

__global__ __launch_bounds__(256) void prep_kernel(
    const float* __restrict__ emb, const float* __restrict__ wl,
    const float* __restrict__ wm, const float* __restrict__ W1,
    unsigned short* __restrict__ feat, unsigned short* __restrict__ w1b,
    float* __restrict__ out)
{
    const int blk = blockIdx.x;

    if (blk < FEAT_BLKS) {
        // ---- feature extraction (unchanged body) ----
        int gid = blk * 256 + threadIdx.x;            // 0 .. B*128-1
        int b   = gid >> 7;
        int c4  = (gid & 127) << 2;                   // channel base

        const float* base = emb + (size_t)b * (S_ * D_) + c4;
        const float l0 = wl[0], l1 = wl[1], l2 = wl[2];
        const float m0 = wm[0], m1 = wm[1], m2 = wm[2];

        nf4 e0 = ntload4(base + 0 * D_);
        nf4 e1 = ntload4(base + 1 * D_);
        nf4 vl = {-3.4e38f, -3.4e38f, -3.4e38f, -3.4e38f};
        nf4 vm = vl;

        #pragma unroll 4
        for (int i = 0; i < 28; ++i) {
            nf4 e2 = ntload4(base + (i + 2) * D_);
            nf4 cv = e0 * l0 + e1 * l1 + e2 * l2;
            vl = fmax4(vl, cv);
            if (i >= 23) {                            // wave-uniform branch
                nf4 cm = e0 * m0 + e1 * m1 + e2 * m2;
                vm = fmax4(vm, cm);
            }
            e0 = e1; e1 = e2;
        }
        unsigned short* frow = feat + (size_t)b * K_;
        store_bf4(frow + c4,            vl);
        store_bf4(frow + D_ + c4,       vm);
        store_bf4(frow + 2 * D_ + c4,   e1);
    } else if (blk < FEAT_BLKS + W1C_BLKS) {
        // ---- W1 fp32 -> bf16 (hides under feat's HBM stream) ----
        int gid = (blk - FEAT_BLKS) * 256 + threadIdx.x;
        nf4 v = ((const nf4*)W1)[gid];
        ushort4 o;
        o.x = f2bf(v.x); o.y = f2bf(v.y); o.z = f2bf(v.z); o.w = f2bf(v.w);
        ((ushort4*)w1b)[gid] = o;
    } else {
        // ---- zero atomics target (replaces hipMemsetAsync) ----
        int gid = (blk - FEAT_BLKS - W1C_BLKS) * 256 + threadIdx.x;
        ((nf4*)out)[gid] = (nf4){0.f, 0.f, 0.f, 0.f};
    }
}

// ---------- kernel 2: GEMM (feature @ W1^T) + tanh + W2 reduce ----------
// M=8192, N=1024, K=1536, both operands K-contiguous. 128x128 tile, BK=64,
// now 8 waves (2m x 4n), each wave 64x32 via 4x2 MFMA 16x16x32 bf16.
// LDS: 2 x (128 rows x 64 k) per operand; chunk within a row XOR-swizzled
// phys_j = j ^ (row&7) (source-permuted for global_load_lds, read with the
// same XOR). 64 lanes x 16B = 1024B per b128 read spread evenly: 8 lanes per
// 16B slot-group across all 32 banks = the 8-cycle LDS floor, no waste.

typedef __bf16 bf16x8 __attribute__((ext_vector_type(8)));
typedef float  f32x4  __attribute__((ext_vector_type(4)));

#define GL2LDS(gp, lp) __builtin_amdgcn_global_load_lds( \
    (const __attribute__((address_space(1))) void*)(gp), \
    (__attribute__((address_space(3))) void*)(lp), 16, 0, 0)

#define NT_ (K_ / 64)   // 24 K-steps

__global__ __launch_bounds__(512) void gemm_kernel(
    const unsigned short* __restrict__ A,    // feature bf16 [8192][1536]
    const unsigned short* __restrict__ Bm,   // W1 bf16 [1024][1536]
    const float* __restrict__ W2,            // [1024]
    float* __restrict__ out)                 // [8192]
{
    __shared__ unsigned short As[2][128 * 64];  // 2 x 16 KB
    __shared__ unsigned short Bs[2][128 * 64];  // 2 x 16 KB

    const int tid  = threadIdx.x;

    // Bijective XCD swizzle (512 blocks, 512%8==0): XCD x gets logical ids
    // [64x, 64x+64) = m-panels 8x..8x+7 with ALL 8 n-blocks each, co-resident.
    const int lg   = (blockIdx.x & 7) * 64 + (blockIdx.x >> 3);
    const int bm   = (lg >> 3) * 128;           // 64 m-blocks
    const int bn   = (lg & 7) * 128;            // 8 n-blocks

    const int lane = tid & 63;
    const int wid  = tid >> 6;                  // 0..7
    const int wm   = wid >> 2;                  // 0..1 (m half, 64 rows)
    const int wn   = wid & 3;                   // 0..3 (n quarter, 32 cols)
    const int lrow = lane & 15;
    const int quad = lane >> 4;

    f32x4 acc[4][2] = {};

    // staging: thread t handles chunks q = t + jj*512, jj=0..1, for A and B.
    // chunk q: row = q>>3, swizzled slot jsw = q&7 -> global j = jsw ^ (row&7).
    int s_row[2], s_jof[2];
    #pragma unroll
    for (int jj = 0; jj < 2; ++jj) {
        int q = tid + jj * 512;
        s_row[jj] = q >> 3;
        s_jof[jj] = (((q & 7) ^ (s_row[jj] & 7)) * 8);
    }

    auto stage = [&](int buf, int kt) {
        const int ko = kt * 64;
        #pragma unroll
        for (int jj = 0; jj < 2; ++jj) {
            int q = tid + jj * 512;
            GL2LDS(A  + (size_t)(bm + s_row[jj]) * K_ + ko + s_jof[jj], &As[buf][q * 8]);
            GL2LDS(Bm + (size_t)(bn + s_row[jj]) * K_ + ko + s_jof[jj], &Bs[buf][q * 8]);
        }
    };

    // prologue: fill buffer 0
    stage(0, 0);
    __syncthreads();   // vmcnt(0) drain + barrier

    for (int kt = 0; kt < NT_; ++kt) {
        const int cur = kt & 1;
        // issue next tile's loads BEFORE compute: latency hides under the
        // ds_reads + MFMAs; the vmcnt(0) drain at the closing barrier pays
        // only the residual.
        if (kt + 1 < NT_) stage(cur ^ 1, kt + 1);

        #pragma unroll
        for (int kk = 0; kk < 2; ++kk) {
            bf16x8 af[4], bf[2];
            const int j = kk * 4 + quad;
            #pragma unroll
            for (int mi = 0; mi < 4; ++mi) {
                int r = wm * 64 + mi * 16 + lrow;
                af[mi] = *(const bf16x8*)&As[cur][r * 64 + ((j ^ (r & 7)) * 8)];
            }
            #pragma unroll
            for (int ni = 0; ni < 2; ++ni) {
                int r = wn * 32 + ni * 16 + lrow;
                bf[ni] = *(const bf16x8*)&Bs[cur][r * 64 + ((j ^ (r & 7)) * 8)];
            }
            #pragma unroll
            for (int mi = 0; mi < 4; ++mi)
                #pragma unroll
                for (int ni = 0; ni < 2; ++ni)
                    acc[mi][ni] = __builtin_amdgcn_mfma_f32_16x16x32_bf16(
                        af[mi], bf[ni], acc[mi][ni], 0, 0, 0);
        }

        __syncthreads();   // drains stage(kt+1); protects As/Bs[cur] reuse
    }

    // epilogue: row = bm + wm*64 + mi*16 + quad*4 + r,
    //           col = bn + wn*32 + ni*16 + lrow
    float w2v[2];
    #pragma unroll
    for (int ni = 0; ni < 2; ++ni)
        w2v[ni] = W2[bn + wn * 32 + ni * 16 + lrow];

    #pragma unroll
    for (int mi = 0; mi < 4; ++mi) {
        #pragma unroll
        for (int r = 0; r < 4; ++r) {
            float s = 0.f;
            #pragma unroll
            for (int ni = 0; ni < 2; ++ni)
                s += fast_tanh(acc[mi][ni][r]) * w2v[ni];
            #pragma unroll
            for (int off = 1; off < 16; off <<= 1)
                s += __shfl_xor(s, off, 64);
            if (lrow == 0)
                atomicAdd(&out[bm + wm * 64 + mi * 16 + quad * 4 + r], s);
        }
    }
}

extern "C" void kernel_launch(void* const* d_in, const int* in_sizes, int n_in,
                              void* d_out, int out_size, void* d_ws, size_t ws_size,
                              hipStream_t stream) {
    const float* emb = (const float*)d_in[0];   // [8192,30,512]
    const float* wl  = (const float*)d_in[1];   // [3]
    const float* wm  = (const float*)d_in[2];   // [3]
    const float* W1  = (const float*)d_in[3];   // [1024,1536]
    const float* W2  = (const float*)d_in[4];   // [1,1024]
    float* out = (float*)d_out;                 // [8192]

    unsigned short* feat = (unsigned short*)d_ws;            // 8192*1536 bf16
    unsigned short* w1b  = feat + (size_t)B_ * K_;           // 1024*1536 bf16

    hipLaunchKernelGGL(prep_kernel, dim3(FEAT_BLKS + W1C_BLKS + ZERO_BLKS),
                       dim3(256), 0, stream, emb, wl, wm, W1, feat, w1b, out);
    hipLaunchKernelGGL(gemm_kernel, dim3((B_ / 128) * (H_ / 128)), dim3(512), 0, stream,
                       feat, w1b, W2, out);
}